// Round 4
// baseline (118.831 us; speedup 1.0000x reference)
//
#include <hip/hip_runtime.h>

// out[c, y, w] = x[p, c, oy, ox]
//   iy = y / 126, jx = w / 126  (clamp to 8 never triggers for y,w < 1024)
//   oy = y - iy*126, ox = w - jx*126, p = iy*9 + jx
// x: (81, 64, 128, 128) f32; out: (64, 1024, 1024) f32. Pure gather, memory-bound.
//
// Round 4: BLOCK-CONTIGUOUS partitioning (the one change vs round 3).
// Rounds 1-3 all ~118 us regardless of load vectorization/density => limiter is
// not instruction shape. Theory: whole-grid-stride made each block jump +16 MB
// every iteration, restarting all its DRAM read streams (504-B runs) -> row
// activate overhead. Now each block owns a contiguous 128 KB output slab and
// walks it sequentially: 1 sequential write stream + 9 monotone read streams
// per block for the slab's lifetime.
//
// Thread granule: one output PAIR (never splits a jx-segment; 8-B aligned on
// both sides; lane-dense 512 B per wave instruction).

__global__ __launch_bounds__(256) void patch_gather_kernel(
    const float* __restrict__ x, float* __restrict__ out,
    unsigned n_pairs, unsigned pairs_per_block) {
    const unsigned tid = threadIdx.x;
    const unsigned b0 = blockIdx.x * pairs_per_block;
    const unsigned b1 = min(b0 + pairs_per_block, n_pairs);
    // walk the slab sequentially: 4 k-steps of 256 lane-dense pairs per iter
    for (unsigned base = b0 + tid; base < b1; base += 1024u) {
        #pragma unroll
        for (int k = 0; k < 4; ++k) {
            const unsigned q = base + (unsigned)k * 256u;
            if (q >= b1) break;                    // exact fit in practice
            const unsigned idx = q << 1;           // flat output index (even)
            const unsigned c  = idx >> 20;         // H*W = 2^20
            const unsigned y  = (idx >> 10) & 1023u;
            const unsigned w0 = idx & 1023u;       // even

            const unsigned iy = y / 126u;          // magic-mul
            const unsigned oy = y - iy * 126u;
            const unsigned jx = w0 / 126u;         // magic-mul
            const unsigned ox = w0 - jx * 126u;    // even

            // addr = ((p*64 + c) << 14) + (oy << 7) + ox,  p = iy*9 + jx
            const size_t addr = ((size_t)(iy * 576u + c) << 14)
                              + ((size_t)jx << 20) + (oy << 7) + ox;
            const float2 v = *reinterpret_cast<const float2*>(&x[addr]);
            *reinterpret_cast<float2*>(&out[idx]) = v;
        }
    }
}

extern "C" void kernel_launch(void* const* d_in, const int* in_sizes, int n_in,
                              void* d_out, int out_size, void* d_ws, size_t ws_size,
                              hipStream_t stream) {
    const float* x = (const float*)d_in[0];
    float* out = (float*)d_out;

    const unsigned n_pairs = (unsigned)(out_size / 2);      // 33,554,432
    const int block = 256;
    const unsigned grid = 2048;                              // 8 blocks/CU, full occupancy
    const unsigned pairs_per_block = (n_pairs + grid - 1) / grid;  // 16384

    patch_gather_kernel<<<grid, block, 0, stream>>>(x, out, n_pairs, pairs_per_block);
}